// Round 1
// baseline (1498.110 us; speedup 1.0000x reference)
//
#include <hip/hip_runtime.h>

// Segment-sum: out[v,:] = sum_{n: X_node[n]==v} H[n,:]
// N=2M rows, D=64, V=100k. fp32.
//
// Round 2 (counting sort + gather) was still ~946us: rocprof showed no single
// kernel >312us, so the time is split across hist (2M global atomics),
// scatter (2M global atomics) and gather (random 256B reads). Global atomics
// resolve at the memory-side coherence point (~16B write-through, ~700cy) ->
// ~7 G atomic/s. Round 3: ZERO global atomics.
//   A: per-block LDS histogram over C=ceil(V/128) coarse buckets -> [B][C] matrix
//   S1/S2: scan matrix columns + column totals -> exact write offsets
//   B2: partition rows into bucket-contiguous perm2[] (packed node<<32|row),
//       LDS cursor atomics only
//   C: one block per bucket: accumulate into 32KB LDS tile (128 nodes x 64
//      feat, LDS f32 atomics; lane->consecutive banks = conflict-free),
//      one coalesced 32KB store. H read nontemporal (no reuse).

constexpr int D     = 64;
constexpr int BHIST = 512;   // blocks for hist/partition passes (= matrix rows)
constexpr int NPB   = 128;   // nodes per coarse bucket
constexpr int MAXC  = 1024;  // max buckets supported by LDS paths (V <= 131072)

// ---------------- Pass A: per-block coarse histogram ----------------
__global__ __launch_bounds__(256) void bucket_hist_kernel(
    const int* __restrict__ idx, int* __restrict__ matB, int N, int C)
{
    __shared__ int h[MAXC];
    for (int c = threadIdx.x; c < C; c += blockDim.x) h[c] = 0;
    __syncthreads();
    int rpb = (N + BHIST - 1) / BHIST;
    int lo = blockIdx.x * rpb;
    int hi = lo + rpb; if (hi > N) hi = N;
    for (int n = lo + threadIdx.x; n < hi; n += blockDim.x)
        atomicAdd(&h[idx[n] >> 7], 1);           // NPB=128 -> bucket = node>>7
    __syncthreads();
    for (int c = threadIdx.x; c < C; c += blockDim.x)
        matB[blockIdx.x * C + c] = h[c];
}

// ------- Pass S1: per-column (bucket) exclusive scan over blocks -------
// One wave per bucket column. In-place: matB -> per-block exclusive prefix.
__global__ __launch_bounds__(256) void scan_mat_kernel(
    int* __restrict__ mat, int* __restrict__ colsum, int C)
{
    int gw   = (blockIdx.x * blockDim.x + threadIdx.x) >> 6;
    int lane = threadIdx.x & 63;
    if (gw >= C) return;
    int c = gw;
    constexpr int VPL = BHIST / 64;              // 8 matrix rows per lane
    int v[VPL], p[VPL];
    int run = 0;
    #pragma unroll
    for (int j = 0; j < VPL; ++j) {
        v[j] = mat[(lane * VPL + j) * C + c];
        p[j] = run;                              // exclusive within lane
        run += v[j];
    }
    int x = run;                                 // lane sum -> wave incl scan
    #pragma unroll
    for (int off = 1; off < 64; off <<= 1) {
        int y = __shfl_up(x, off);
        if (lane >= off) x += y;
    }
    int lane_excl = x - run;
    #pragma unroll
    for (int j = 0; j < VPL; ++j)
        mat[(lane * VPL + j) * C + c] = lane_excl + p[j];
    if (lane == 63) colsum[c] = x;               // column total
}

// ------- Pass S2: exclusive scan of column totals -> bucket bases -------
__global__ __launch_bounds__(1024) void scan_cols_kernel(
    const int* __restrict__ colsum, int* __restrict__ colbase, int C, int N)
{
    __shared__ int tmp[1024];
    int t = threadIdx.x;
    if (C <= 1024) {
        int x = (t < C) ? colsum[t] : 0;
        tmp[t] = x;
        __syncthreads();
        for (int off = 1; off < 1024; off <<= 1) {
            int y = (t >= off) ? tmp[t - off] : 0;
            __syncthreads();
            tmp[t] += y;
            __syncthreads();
        }
        if (t < C) colbase[t] = tmp[t] - x;      // exclusive
        if (t == 0) colbase[C] = N;              // total rows
    } else {
        if (t == 0) {
            int run = 0;
            for (int c = 0; c < C; ++c) { colbase[c] = run; run += colsum[c]; }
            colbase[C] = run;
        }
    }
}

// ------- Pass B2: partition rows into bucket-contiguous perm2 -------
// Zero global atomics: cursors = colbase[c] + per-block exclusive prefix.
__global__ __launch_bounds__(256) void partition_kernel(
    const int* __restrict__ idx, const int* __restrict__ matP,
    const int* __restrict__ colbase, long long* __restrict__ perm2,
    int N, int C)
{
    __shared__ int cur[MAXC];
    for (int c = threadIdx.x; c < C; c += blockDim.x)
        cur[c] = colbase[c] + matP[blockIdx.x * C + c];
    __syncthreads();
    int rpb = (N + BHIST - 1) / BHIST;           // must match bucket_hist
    int lo = blockIdx.x * rpb;
    int hi = lo + rpb; if (hi > N) hi = N;
    for (int n = lo + threadIdx.x; n < hi; n += blockDim.x) {
        int node = idx[n];
        int pos  = atomicAdd(&cur[node >> 7], 1);   // LDS atomic
        long long pv = ((long long)node << 32) | (unsigned)n;
        __builtin_nontemporal_store(pv, &perm2[pos]);
    }
}

// ------- Pass C: one block per bucket, accumulate in LDS, coalesced out ----
__global__ __launch_bounds__(512) void accum_kernel(
    const float* __restrict__ H, const long long* __restrict__ perm2,
    const int* __restrict__ colbase, float* __restrict__ out, int V)
{
    __shared__ float acc[NPB * D];               // 32 KB
    int tid = threadIdx.x;
    for (int e = tid; e < NPB * D; e += 512) acc[e] = 0.f;
    __syncthreads();

    int c     = blockIdx.x;
    int start = colbase[c];
    int end   = colbase[c + 1];
    int w     = tid >> 6;
    int lane  = tid & 63;

    // 8 waves x 4-row chunks, block-stride 32 rows. Wave-uniform guards.
    for (int r = start + w * 4; r < end; r += 32) {
        #pragma unroll
        for (int u = 0; u < 4; ++u) {
            int rr = r + u;
            if (rr < end) {
                long long pv = perm2[rr];        // same addr across wave
                int n     = (int)(pv & 0xffffffffLL);
                int local = ((int)(pv >> 32)) & (NPB - 1);
                float val = __builtin_nontemporal_load(&H[(size_t)n * D + lane]);
                atomicAdd(&acc[local * D + lane], val);   // LDS f32 atomic
            }
        }
    }
    __syncthreads();

    int vbase = c * NPB;
    int nn = V - vbase; if (nn > NPB) nn = NPB;  // last bucket may be partial
    for (int e = tid; e < nn * D; e += 512)
        __builtin_nontemporal_store(acc[e], &out[(size_t)vbase * D + e]);
}

// ---- fallback (only if ws too small / C too large): direct atomic scatter ----
__global__ __launch_bounds__(256) void scatter_atomic_kernel(
    const float4* __restrict__ H4, const int* __restrict__ idx,
    float* __restrict__ out, int n_rows)
{
    long long t = (long long)blockIdx.x * blockDim.x + threadIdx.x;
    int n = (int)(t >> 4), q = (int)(t & 15);
    if (n >= n_rows) return;
    int node = idx[n];
    float4 v = H4[(size_t)n * 16 + q];
    float* o = out + (size_t)node * D + q * 4;
    atomicAdd(o + 0, v.x); atomicAdd(o + 1, v.y);
    atomicAdd(o + 2, v.z); atomicAdd(o + 3, v.w);
}

static inline size_t align_up(size_t x, size_t a) { return (x + a - 1) & ~(a - 1); }

extern "C" void kernel_launch(void* const* d_in, const int* in_sizes, int n_in,
                              void* d_out, int out_size, void* d_ws, size_t ws_size,
                              hipStream_t stream) {
    const float* H = (const float*)d_in[0];
    const int* idx = (const int*)d_in[1];
    float* out     = (float*)d_out;
    int N = in_sizes[1];
    int V = out_size / D;
    int C = (V + NPB - 1) / NPB;

    // workspace layout: matB[BHIST*C] | colsum[C] | colbase[C+1] | perm2[N]
    size_t off_mat   = 0;
    size_t off_csum  = align_up(off_mat  + (size_t)BHIST * C * 4, 256);
    size_t off_cbase = align_up(off_csum + (size_t)C * 4, 256);
    size_t off_perm  = align_up(off_cbase + ((size_t)C + 1) * 4, 256);
    size_t need      = off_perm + (size_t)N * 8;

    if (ws_size < need || C > MAXC) {
        // fallback: atomic scatter (correct, slower)
        hipMemsetAsync(d_out, 0, (size_t)out_size * sizeof(float), stream);
        long long total = (long long)N * 16;
        scatter_atomic_kernel<<<(int)((total + 255) / 256), 256, 0, stream>>>(
            (const float4*)H, idx, out, N);
        return;
    }

    char* ws = (char*)d_ws;
    int* matB         = (int*)(ws + off_mat);
    int* colsum       = (int*)(ws + off_csum);
    int* colbase      = (int*)(ws + off_cbase);
    long long* perm2  = (long long*)(ws + off_perm);

    // no memsets needed: every workspace word is written before it is read
    bucket_hist_kernel<<<BHIST, 256, 0, stream>>>(idx, matB, N, C);
    scan_mat_kernel<<<(C + 3) / 4, 256, 0, stream>>>(matB, colsum, C);
    scan_cols_kernel<<<1, 1024, 0, stream>>>(colsum, colbase, C, N);
    partition_kernel<<<BHIST, 256, 0, stream>>>(idx, matB, colbase, perm2, N, C);
    accum_kernel<<<C, 512, 0, stream>>>(H, perm2, colbase, out, V);
}

// Round 2
// 1441.037 us; speedup vs baseline: 1.0396x; 1.0396x over previous
//
#include <hip/hip_runtime.h>

// Segment-sum: out[v,:] = sum_{n: X_node[n]==v} H[n,:]
// N=2M rows, D=64, V=100k. fp32.
//
// Round 3 post-mortem: accum was 895us @ 324 GB/s, VALUBusy 3%, VGPR=8 ->
// latency-serialized: the per-row `if (rr<end)` guard around each load made
// the compiler emit load->waitcnt->load->waitcnt per row (1 load in flight).
// Round 4: branch-free accum. Each wave loads 64 packed perm2 records in ONE
// coalesced 512B load, then shfl-broadcasts 8 at a time and issues 8
// independent H-row loads back-to-back (8x256B in flight per wave), then 8
// fire-and-forget LDS f32 atomics. Nontemporal hints removed everywhere:
// L3 absorbs ~half the H stream (FETCH 258MB < 512MB) and perm2 scattered
// 8B stores need L2 write-coalescing.

constexpr int D     = 64;
constexpr int BHIST = 512;   // blocks for hist/partition passes (= matrix rows)
constexpr int NPB   = 128;   // nodes per coarse bucket
constexpr int MAXC  = 1024;  // max buckets supported by LDS paths (V <= 131072)

// ---------------- Pass A: per-block coarse histogram ----------------
__global__ __launch_bounds__(256) void bucket_hist_kernel(
    const int* __restrict__ idx, int* __restrict__ matB, int N, int C)
{
    __shared__ int h[MAXC];
    for (int c = threadIdx.x; c < C; c += blockDim.x) h[c] = 0;
    __syncthreads();
    int rpb = (N + BHIST - 1) / BHIST;
    int lo = blockIdx.x * rpb;
    int hi = lo + rpb; if (hi > N) hi = N;
    for (int n = lo + threadIdx.x; n < hi; n += blockDim.x)
        atomicAdd(&h[idx[n] >> 7], 1);           // NPB=128 -> bucket = node>>7
    __syncthreads();
    for (int c = threadIdx.x; c < C; c += blockDim.x)
        matB[blockIdx.x * C + c] = h[c];
}

// ------- Pass S1: per-column (bucket) exclusive scan over blocks -------
// One wave per bucket column. In-place: matB -> per-block exclusive prefix.
__global__ __launch_bounds__(256) void scan_mat_kernel(
    int* __restrict__ mat, int* __restrict__ colsum, int C)
{
    int gw   = (blockIdx.x * blockDim.x + threadIdx.x) >> 6;
    int lane = threadIdx.x & 63;
    if (gw >= C) return;
    int c = gw;
    constexpr int VPL = BHIST / 64;              // 8 matrix rows per lane
    int v[VPL], p[VPL];
    int run = 0;
    #pragma unroll
    for (int j = 0; j < VPL; ++j) {
        v[j] = mat[(lane * VPL + j) * C + c];
        p[j] = run;                              // exclusive within lane
        run += v[j];
    }
    int x = run;                                 // lane sum -> wave incl scan
    #pragma unroll
    for (int off = 1; off < 64; off <<= 1) {
        int y = __shfl_up(x, off);
        if (lane >= off) x += y;
    }
    int lane_excl = x - run;
    #pragma unroll
    for (int j = 0; j < VPL; ++j)
        mat[(lane * VPL + j) * C + c] = lane_excl + p[j];
    if (lane == 63) colsum[c] = x;               // column total
}

// ------- Pass S2: exclusive scan of column totals -> bucket bases -------
__global__ __launch_bounds__(1024) void scan_cols_kernel(
    const int* __restrict__ colsum, int* __restrict__ colbase, int C, int N)
{
    __shared__ int tmp[1024];
    int t = threadIdx.x;
    if (C <= 1024) {
        int x = (t < C) ? colsum[t] : 0;
        tmp[t] = x;
        __syncthreads();
        for (int off = 1; off < 1024; off <<= 1) {
            int y = (t >= off) ? tmp[t - off] : 0;
            __syncthreads();
            tmp[t] += y;
            __syncthreads();
        }
        if (t < C) colbase[t] = tmp[t] - x;      // exclusive
        if (t == 0) colbase[C] = N;              // total rows
    } else {
        if (t == 0) {
            int run = 0;
            for (int c = 0; c < C; ++c) { colbase[c] = run; run += colsum[c]; }
            colbase[C] = run;
        }
    }
}

// ------- Pass B2: partition rows into bucket-contiguous perm2 -------
// Zero global atomics: cursors = colbase[c] + per-block exclusive prefix.
__global__ __launch_bounds__(256) void partition_kernel(
    const int* __restrict__ idx, const int* __restrict__ matP,
    const int* __restrict__ colbase, long long* __restrict__ perm2,
    int N, int C)
{
    __shared__ int cur[MAXC];
    for (int c = threadIdx.x; c < C; c += blockDim.x)
        cur[c] = colbase[c] + matP[blockIdx.x * C + c];
    __syncthreads();
    int rpb = (N + BHIST - 1) / BHIST;           // must match bucket_hist
    int lo = blockIdx.x * rpb;
    int hi = lo + rpb; if (hi > N) hi = N;
    for (int n = lo + threadIdx.x; n < hi; n += blockDim.x) {
        int node = idx[n];
        int pos  = atomicAdd(&cur[node >> 7], 1);   // LDS atomic
        perm2[pos] = ((long long)node << 32) | (unsigned)n;  // plain store: L2 coalesces
    }
}

// ------- Pass C: one block per bucket, accumulate in LDS, coalesced out ----
// 8 waves. Each wave owns full 64-row chunks (stride 8 chunks). Per chunk:
// ONE coalesced 512B perm2 load (1 record/lane), then branch-free inner:
// shfl-broadcast 8 records -> 8 independent H loads -> 8 LDS atomics.
__global__ __launch_bounds__(512) void accum_kernel(
    const float* __restrict__ H, const long long* __restrict__ perm2,
    const int* __restrict__ colbase, float* __restrict__ out, int V)
{
    __shared__ float acc[NPB * D];               // 32 KB
    int tid = threadIdx.x;
    for (int e = tid; e < NPB * D; e += 512) acc[e] = 0.f;
    __syncthreads();

    int c     = blockIdx.x;
    int start = colbase[c];
    int cnt   = colbase[c + 1] - start;
    int w     = tid >> 6;
    int lane  = tid & 63;

    int nchunks = cnt >> 6;                      // full 64-row chunks
    int tail    = cnt & 63;

    for (int ch = w; ch < nchunks; ch += 8) {
        int base = start + (ch << 6);
        long long pv = perm2[base + lane];       // one coalesced 512B load
        #pragma unroll
        for (int g = 0; g < 8; ++g) {
            float val[8]; int loc[8];
            #pragma unroll
            for (int j = 0; j < 8; ++j) {        // 8 independent loads in flight
                long long p = __shfl(pv, g * 8 + j);
                int n  = (int)(p & 0xffffffffLL);
                loc[j] = ((int)(p >> 32)) & (NPB - 1);
                val[j] = H[(size_t)n * D + lane];
            }
            #pragma unroll
            for (int j = 0; j < 8; ++j)          // fire-and-forget ds_add_f32
                atomicAdd(&acc[loc[j] * D + lane], val[j]);
        }
    }

    // tail (<64 rows): one wave handles it
    if (tail && w == (nchunks & 7)) {
        int base = start + (nchunks << 6);
        long long pv = (lane < tail) ? perm2[base + lane] : 0;
        for (int i = 0; i < tail; ++i) {
            long long p = __shfl(pv, i);
            int n   = (int)(p & 0xffffffffLL);
            int l_  = ((int)(p >> 32)) & (NPB - 1);
            atomicAdd(&acc[l_ * D + lane], H[(size_t)n * D + lane]);
        }
    }
    __syncthreads();

    int vbase = c * NPB;
    int nn = V - vbase; if (nn > NPB) nn = NPB;  // last bucket may be partial
    for (int e = tid; e < nn * D; e += 512)
        out[(size_t)vbase * D + e] = acc[e];
}

// ---- fallback (only if ws too small / C too large): direct atomic scatter ----
__global__ __launch_bounds__(256) void scatter_atomic_kernel(
    const float4* __restrict__ H4, const int* __restrict__ idx,
    float* __restrict__ out, int n_rows)
{
    long long t = (long long)blockIdx.x * blockDim.x + threadIdx.x;
    int n = (int)(t >> 4), q = (int)(t & 15);
    if (n >= n_rows) return;
    int node = idx[n];
    float4 v = H4[(size_t)n * 16 + q];
    float* o = out + (size_t)node * D + q * 4;
    atomicAdd(o + 0, v.x); atomicAdd(o + 1, v.y);
    atomicAdd(o + 2, v.z); atomicAdd(o + 3, v.w);
}

static inline size_t align_up(size_t x, size_t a) { return (x + a - 1) & ~(a - 1); }

extern "C" void kernel_launch(void* const* d_in, const int* in_sizes, int n_in,
                              void* d_out, int out_size, void* d_ws, size_t ws_size,
                              hipStream_t stream) {
    const float* H = (const float*)d_in[0];
    const int* idx = (const int*)d_in[1];
    float* out     = (float*)d_out;
    int N = in_sizes[1];
    int V = out_size / D;
    int C = (V + NPB - 1) / NPB;

    // workspace layout: matB[BHIST*C] | colsum[C] | colbase[C+1] | perm2[N]
    size_t off_mat   = 0;
    size_t off_csum  = align_up(off_mat  + (size_t)BHIST * C * 4, 256);
    size_t off_cbase = align_up(off_csum + (size_t)C * 4, 256);
    size_t off_perm  = align_up(off_cbase + ((size_t)C + 1) * 4, 256);
    size_t need      = off_perm + (size_t)N * 8;

    if (ws_size < need || C > MAXC) {
        // fallback: atomic scatter (correct, slower)
        hipMemsetAsync(d_out, 0, (size_t)out_size * sizeof(float), stream);
        long long total = (long long)N * 16;
        scatter_atomic_kernel<<<(int)((total + 255) / 256), 256, 0, stream>>>(
            (const float4*)H, idx, out, N);
        return;
    }

    char* ws = (char*)d_ws;
    int* matB         = (int*)(ws + off_mat);
    int* colsum       = (int*)(ws + off_csum);
    int* colbase      = (int*)(ws + off_cbase);
    long long* perm2  = (long long*)(ws + off_perm);

    // no memsets needed: every workspace word is written before it is read
    bucket_hist_kernel<<<BHIST, 256, 0, stream>>>(idx, matB, N, C);
    scan_mat_kernel<<<(C + 3) / 4, 256, 0, stream>>>(matB, colsum, C);
    scan_cols_kernel<<<1, 1024, 0, stream>>>(colsum, colbase, C, N);
    partition_kernel<<<BHIST, 256, 0, stream>>>(idx, matB, colbase, perm2, N, C);
    accum_kernel<<<C, 512, 0, stream>>>(H, perm2, colbase, out, V);
}